// Round 4
// baseline (304.731 us; speedup 1.0000x reference)
//
#include <hip/hip_runtime.h>
#include <hip/hip_fp16.h>
#include <cstdint>
#include <cstddef>

// ---------------------------------------------------------------------------
// VectorQuantizerEMA on MI355X.  B=8,S=2048,D=256,K=4096 -> N=16384 tokens.
//   1) split z / codebook into fp16 (h1, h2*2^11) packed rows (+ fp64 norms)
//   2) distance GEMM: 3x mfma_f32_16x16x32_f16 per frag (h1h1 -> acc1,
//      cross terms -> acc2), fp64 epilogue argmin -> 64 candidates/token
//   3) merge candidates; gather codebook row -> out; block loss partials;
//      distributed atomic scatter of n / dw
//   4) new_weight elementwise; new_count normalize + loss finalize
// R1: removed same-address atomic chains (429us -> gone).
// R2: 2-phase dbuf pipeline: only 187->177us, MfmaUtil stuck 25% -> phase
//     lockstep, not load latency, is the stall.
// R3: vq_gemm rewritten as 256x128-tile 8-wave (512thr) schedule with
//     2 sub-phases per K-step and COUNTED vmcnt (4/2, never 0 in loop):
//     staging split {B,A-half1 | A-half2}, issue order B0,B1,Aj0,Aj1|Aj2,Aj3.
//     Raw s_barrier + asm lgkmcnt(0) + sched_barrier(0) (rule 18), setprio
//     around MFMA clusters. LDS 2x48KB dynamic. Merge/finish unchanged.
// ---------------------------------------------------------------------------

#define N_TOK 16384
#define DIM   256
#define K_CB  4096

typedef _Float16 h8    __attribute__((ext_vector_type(8)));
typedef float    f32x4 __attribute__((ext_vector_type(4)));

// ---- ws layout (bytes) ----
#define WS_ZPACK   0u            // N_TOK * 512 halves  = 16 MB
#define WS_CPACK   16777216u     // K_CB * 512 halves   = 4 MB
#define WS_CNORM   20971520u     // K_CB doubles        = 32 KB
#define WS_CANDV   21004288u     // N_TOK * 64 doubles  = 8 MB
#define WS_CANDI   29392896u     // N_TOK * 64 int      = 4 MB
#define WS_DW      33587200u     // K_CB * DIM float    = 4 MB
#define WS_NACC    37781504u     // K_CB float          = 16 KB
#define WS_LPART   37797888u     // 4096 float block loss partials
#define WS_MPART   37814272u     // 4096 float block mask partials
#define WS_ZERO_BYTES (4194304u + 16384u)

__device__ __forceinline__ void gload_lds16(const void* g, void* l) {
  __builtin_amdgcn_global_load_lds(
      (const __attribute__((address_space(1))) uint32_t*)g,
      (__attribute__((address_space(3))) uint32_t*)l, 16, 0, 0);
}

// ---- 1a: split z into packed fp16 pair rows --------------------------------
__global__ void vq_split_z(const float* __restrict__ z, unsigned short* __restrict__ pack) {
  int tid = blockIdx.x * 256 + threadIdx.x;       // over N_TOK*64
  int row = tid >> 6, c4 = tid & 63;
  float4 v = reinterpret_cast<const float4*>(z)[tid];
  float x[4] = {v.x, v.y, v.z, v.w};
  union { _Float16 h[4]; ushort4 u; } a, b;
#pragma unroll
  for (int i = 0; i < 4; ++i) {
    _Float16 h1 = (_Float16)x[i];
    float lo = x[i] - (float)h1;
    a.h[i] = h1;
    b.h[i] = (_Float16)(lo * 2048.0f);   // scaled to avoid fp16 denormal loss
  }
  reinterpret_cast<ushort4*>(pack)[row * 128 + c4]      = a.u;
  reinterpret_cast<ushort4*>(pack)[row * 128 + 64 + c4] = b.u;
}

// ---- 1b: split codebook + fp64 row norms -----------------------------------
__global__ void vq_split_c(const float* __restrict__ cb, unsigned short* __restrict__ pack,
                           double* __restrict__ cnorm) {
  int w = threadIdx.x >> 6, l = threadIdx.x & 63;
  int row = blockIdx.x * 4 + w;
  float4 v = reinterpret_cast<const float4*>(cb)[row * 64 + l];
  float x[4] = {v.x, v.y, v.z, v.w};
  union { _Float16 h[4]; ushort4 u; } a, b;
  double ss = 0.0;
#pragma unroll
  for (int i = 0; i < 4; ++i) {
    _Float16 h1 = (_Float16)x[i];
    float lo = x[i] - (float)h1;
    a.h[i] = h1;
    b.h[i] = (_Float16)(lo * 2048.0f);
    ss += (double)x[i] * (double)x[i];
  }
  reinterpret_cast<ushort4*>(pack)[row * 128 + l]      = a.u;
  reinterpret_cast<ushort4*>(pack)[row * 128 + 64 + l] = b.u;
  for (int off = 1; off < 64; off <<= 1) ss += __shfl_xor(ss, off);
  if (l == 0) cnorm[row] = ss;
}

// ---- 2: distance GEMM + per-block argmin -----------------------------------
// 512 thr = 8 waves (4M x 2N). Tile 256 tokens x 128 entries, BK=32 dims.
// LDS buffer (48KB): A 256 rows x 128B (32KB) | B 128 rows x 128B (16KB);
// row = [8 chunks of 16B], chunks 0-3 = h1 k0..31, 4-7 = h2 (x2048);
// stored chunk = logical ^ (row&7)  (swizzle applied on global SOURCE addr;
// global_load_lds writes linearly). Double-buffered: 96KB dynamic LDS.
//
// Per K-tile, 2 sub-phases:
//   ph0: ds_read B-frags(8) + A m0,m1(4); issue next-tile B0,B1,Aj0,Aj1;
//        barrier; lgkm(0); 24 MFMA; vmcnt(4); barrier.
//   ph1: ds_read A m2,m3(4); issue next-tile Aj2,Aj3;
//        barrier; lgkm(0); 24 MFMA; vmcnt(2); barrier.
// Staging regions: Aj0={rows 0-31,64-95}, Aj1={128-159,192-223} (ph0 rows),
// Aj2/Aj3 = +32 (ph1 rows); issue order makes counted vmcnt exact.
__global__ __launch_bounds__(512, 2) void vq_gemm(
    const unsigned short* __restrict__ zpack, const unsigned short* __restrict__ cpack,
    const double* __restrict__ cnorm,
    double* __restrict__ cand_val, int* __restrict__ cand_idx) {
  extern __shared__ unsigned char lds[];   // 98304 bytes

  // XCD-aware bijective swizzle: 2048 blocks = 8 XCDs x 256.
  // Within an XCD chunk: mb fast (64), nb slow (4) -> A-tile L2 reuse.
  const int bid  = blockIdx.x;
  const int wgid = (bid & 7) * 256 + (bid >> 3);
  const int mb   = wgid & 63;          // 0..63
  const int nb   = wgid >> 6;          // 0..31
  const int token0 = mb * 256, entry0 = nb * 128;

  const int tx = threadIdx.x;
  const int w  = tx >> 6, l = tx & 63;
  const int waveM = w >> 1, waveN = w & 1;
  const int fr = l & 15, fk = l >> 4;

  // staging constants
  const int ch  = tx & 7;              // stored chunk this thread fills
  const int rr  = tx >> 3;             // 0..63
  const int lc  = ch ^ (rr & 7);       // logical chunk to fetch
  const int soff = (lc >> 2) * 512 + (lc & 3) * 16;
  int rowA[4];
  rowA[0] = (rr >> 5) * 64 + (rr & 31);        // rows 0-31, 64-95
  rowA[1] = 128 + rowA[0];                     // rows 128-159, 192-223
  rowA[2] = rowA[0] + 32;                      // rows 32-63, 96-127
  rowA[3] = rowA[1] + 32;                      // rows 160-191, 224-255
  const unsigned char* zb  = (const unsigned char*)zpack;
  const unsigned char* cbp = (const unsigned char*)cpack;
  const unsigned char* srcA[4]; const unsigned char* srcB[2];
  unsigned dA[4], dB[2];
#pragma unroll
  for (int j = 0; j < 4; ++j) {
    srcA[j] = zb + (size_t)(token0 + rowA[j]) * 1024 + soff;
    dA[j]   = (unsigned)(rowA[j] * 128 + ch * 16);
  }
#pragma unroll
  for (int k = 0; k < 2; ++k) {
    srcB[k] = cbp + (size_t)(entry0 + k * 64 + rr) * 1024 + soff;
    dB[k]   = 32768u + (unsigned)((k * 64 + rr) * 128 + ch * 16);
  }

  f32x4 zero = {0.f, 0.f, 0.f, 0.f};
  f32x4 acc1[4][4], acc2[4][4];
#pragma unroll
  for (int m = 0; m < 4; ++m)
#pragma unroll
    for (int n = 0; n < 4; ++n) { acc1[m][n] = zero; acc2[m][n] = zero; }

  // prologue: stage tile 0 into buffer 0, issue order B0,B1,A0,A1,A2,A3
  gload_lds16(srcB[0], &lds[dB[0]]);
  gload_lds16(srcB[1], &lds[dB[1]]);
  gload_lds16(srcA[0], &lds[dA[0]]);
  gload_lds16(srcA[1], &lds[dA[1]]);
  gload_lds16(srcA[2], &lds[dA[2]]);
  gload_lds16(srcA[3], &lds[dA[3]]);
  asm volatile("s_waitcnt vmcnt(2)" ::: "memory");   // B+A0+A1 landed
  __builtin_amdgcn_s_barrier();

  h8 b1f[4], b2f[4];
#pragma unroll 2
  for (int t = 0; t < 8; ++t) {
    const unsigned base  = (unsigned)(t & 1) * 49152u;
    const unsigned nbase = (unsigned)((t + 1) & 1) * 49152u;

    // ---------------- phase 0 ----------------
    h8 a1f[2], a2f[2];
#pragma unroll
    for (int n = 0; n < 4; ++n) {
      int r = waveN * 64 + n * 16 + fr;
      int st0 = (fk) ^ (r & 7), st1 = (4 + fk) ^ (r & 7);
      b1f[n] = *(const h8*)&lds[base + 32768u + r * 128 + st0 * 16];
      b2f[n] = *(const h8*)&lds[base + 32768u + r * 128 + st1 * 16];
    }
#pragma unroll
    for (int m = 0; m < 2; ++m) {
      int r = waveM * 64 + m * 16 + fr;
      int st0 = (fk) ^ (r & 7), st1 = (4 + fk) ^ (r & 7);
      a1f[m] = *(const h8*)&lds[base + r * 128 + st0 * 16];
      a2f[m] = *(const h8*)&lds[base + r * 128 + st1 * 16];
    }
    if (t < 7) {
      gload_lds16(srcB[0] + (t + 1) * 64, &lds[nbase + dB[0]]);
      gload_lds16(srcB[1] + (t + 1) * 64, &lds[nbase + dB[1]]);
      gload_lds16(srcA[0] + (t + 1) * 64, &lds[nbase + dA[0]]);
      gload_lds16(srcA[1] + (t + 1) * 64, &lds[nbase + dA[1]]);
    }
    __builtin_amdgcn_s_barrier();
    asm volatile("s_waitcnt lgkmcnt(0)" ::: "memory");
    __builtin_amdgcn_sched_barrier(0);
    __builtin_amdgcn_s_setprio(1);
#pragma unroll
    for (int m = 0; m < 2; ++m)
#pragma unroll
      for (int n = 0; n < 4; ++n) {
        acc1[m][n] = __builtin_amdgcn_mfma_f32_16x16x32_f16(a1f[m], b1f[n], acc1[m][n], 0, 0, 0);
        acc2[m][n] = __builtin_amdgcn_mfma_f32_16x16x32_f16(a1f[m], b2f[n], acc2[m][n], 0, 0, 0);
        acc2[m][n] = __builtin_amdgcn_mfma_f32_16x16x32_f16(a2f[m], b1f[n], acc2[m][n], 0, 0, 0);
      }
    __builtin_amdgcn_s_setprio(0);
    __builtin_amdgcn_sched_barrier(0);
    if (t < 7) asm volatile("s_waitcnt vmcnt(4)" ::: "memory");  // this tile's A2,A3 done
    else       asm volatile("s_waitcnt vmcnt(0)" ::: "memory");
    __builtin_amdgcn_s_barrier();

    // ---------------- phase 1 ----------------
#pragma unroll
    for (int m = 0; m < 2; ++m) {
      int r = waveM * 64 + (m + 2) * 16 + fr;
      int st0 = (fk) ^ (r & 7), st1 = (4 + fk) ^ (r & 7);
      a1f[m] = *(const h8*)&lds[base + r * 128 + st0 * 16];
      a2f[m] = *(const h8*)&lds[base + r * 128 + st1 * 16];
    }
    if (t < 7) {
      gload_lds16(srcA[2] + (t + 1) * 64, &lds[nbase + dA[2]]);
      gload_lds16(srcA[3] + (t + 1) * 64, &lds[nbase + dA[3]]);
    }
    __builtin_amdgcn_s_barrier();
    asm volatile("s_waitcnt lgkmcnt(0)" ::: "memory");
    __builtin_amdgcn_sched_barrier(0);
    __builtin_amdgcn_s_setprio(1);
#pragma unroll
    for (int m = 0; m < 2; ++m)
#pragma unroll
      for (int n = 0; n < 4; ++n) {
        acc1[m + 2][n] = __builtin_amdgcn_mfma_f32_16x16x32_f16(a1f[m], b1f[n], acc1[m + 2][n], 0, 0, 0);
        acc2[m + 2][n] = __builtin_amdgcn_mfma_f32_16x16x32_f16(a1f[m], b2f[n], acc2[m + 2][n], 0, 0, 0);
        acc2[m + 2][n] = __builtin_amdgcn_mfma_f32_16x16x32_f16(a2f[m], b1f[n], acc2[m + 2][n], 0, 0, 0);
      }
    __builtin_amdgcn_s_setprio(0);
    __builtin_amdgcn_sched_barrier(0);
    if (t < 7) {
      asm volatile("s_waitcnt vmcnt(2)" ::: "memory");  // next tile's B+A0+A1 done
      __builtin_amdgcn_s_barrier();
    }
  }

  // epilogue: d = |c|^2 - 2*(acc1 + acc2/2048) in fp64, per-token argmin
  double cn[4];
#pragma unroll
  for (int n = 0; n < 4; ++n) cn[n] = cnorm[entry0 + waveN * 64 + n * 16 + fr];

#pragma unroll
  for (int m = 0; m < 4; ++m) {
#pragma unroll
    for (int rI = 0; rI < 4; ++rI) {
      double bd = 1e300; int bi = 0x7fffffff;
#pragma unroll
      for (int n = 0; n < 4; ++n) {
        double s = (double)acc1[m][n][rI] + (double)acc2[m][n][rI] * (1.0 / 2048.0);
        double d = cn[n] - 2.0 * s;
        int e = entry0 + waveN * 64 + n * 16 + fr;
        if (d < bd || (d == bd && e < bi)) { bd = d; bi = e; }
      }
      for (int off = 1; off < 16; off <<= 1) {   // reduce across 16 fragment cols
        double od = __shfl_xor(bd, off);
        int    oi = __shfl_xor(bi, off);
        if (od < bd || (od == bd && oi < bi)) { bd = od; bi = oi; }
      }
      if (fr == 0) {
        int token = token0 + waveM * 64 + m * 16 + fk * 4 + rI;
        int slot  = nb * 2 + waveN;              // 64 slots per token
        cand_val[(size_t)token * 64 + slot] = bd;
        cand_idx[(size_t)token * 64 + slot] = bi;
      }
    }
  }
}

// ---- 3: merge candidates; out/indices; block loss partials; scatter n/dw ---
__global__ void vq_merge_scatter(
    const double* __restrict__ cand_val, const int* __restrict__ cand_idx,
    const float* __restrict__ z, const float* __restrict__ mask,
    const float* __restrict__ codebook,
    float* __restrict__ out0, float* __restrict__ out_idx,
    float* __restrict__ dw, float* __restrict__ nacc,
    float* __restrict__ loss_part, float* __restrict__ mask_part) {
  __shared__ float ls[4], ms[4];
  int w = threadIdx.x >> 6, l = threadIdx.x & 63;
  int token = blockIdx.x * 4 + w;

  double bv = cand_val[(size_t)token * 64 + l];
  int    bi = cand_idx[(size_t)token * 64 + l];
  for (int off = 1; off < 64; off <<= 1) {
    double ov = __shfl_xor(bv, off);
    int    oi = __shfl_xor(bi, off);
    if (ov < bv || (ov == bv && oi < bi)) { bv = ov; bi = oi; }
  }

  float4 cv = reinterpret_cast<const float4*>(codebook)[(size_t)bi * 64 + l];
  reinterpret_cast<float4*>(out0)[(size_t)token * 64 + l] = cv;   // out == quantized
  float4 zv = reinterpret_cast<const float4*>(z)[(size_t)token * 64 + l];

  float dx = zv.x - cv.x, dy = zv.y - cv.y, dz = zv.z - cv.z, dww = zv.w - cv.w;
  float ssd = dx * dx + dy * dy + dz * dz + dww * dww;
  for (int off = 1; off < 64; off <<= 1) ssd += __shfl_xor(ssd, off);

  float mk = mask[token];
  if (l == 0) {
    out_idx[token] = (float)bi;
    ls[w] = mk * ssd * (1.0f / 256.0f);
    ms[w] = mk;
    atomicAdd(&nacc[bi], mk);          // ~4 avg collisions/addr: pipelines fine
  }
  if (mk != 0.0f) {
    float* p = dw + (size_t)bi * 256 + l * 4;
    atomicAdd(p + 0, mk * zv.x);
    atomicAdd(p + 1, mk * zv.y);
    atomicAdd(p + 2, mk * zv.z);
    atomicAdd(p + 3, mk * zv.w);
  }
  __syncthreads();
  if (threadIdx.x == 0) {
    loss_part[blockIdx.x] = ls[0] + ls[1] + ls[2] + ls[3];
    mask_part[blockIdx.x] = ms[0] + ms[1] + ms[2] + ms[3];
  }
}

// ---- 4a: new_weight --------------------------------------------------------
__global__ void vq_finish_weight(const float* __restrict__ ew, const float* __restrict__ dw,
                                 float* __restrict__ nw) {
  int i = blockIdx.x * 256 + threadIdx.x;       // over K*D/4
  float4 e = reinterpret_cast<const float4*>(ew)[i];
  float4 d = reinterpret_cast<const float4*>(dw)[i];
  float4 o;
  o.x = 0.99f * e.x + 0.01f * d.x;
  o.y = 0.99f * e.y + 0.01f * d.y;
  o.z = 0.99f * e.z + 0.01f * d.z;
  o.w = 0.99f * e.w + 0.01f * d.w;
  reinterpret_cast<float4*>(nw)[i] = o;
}

// ---- 4b: new_count normalize + deterministic loss reduce -------------------
__global__ void vq_finish_count(const float* __restrict__ ec, const float* __restrict__ nacc,
                                const float* __restrict__ loss_part,
                                const float* __restrict__ mask_part,
                                float* __restrict__ out_count, float* __restrict__ out_loss) {
  __shared__ float nc_s[K_CB];
  __shared__ float red[256];
  int tid = threadIdx.x;
  float part = 0.f;
  for (int i = tid; i < K_CB; i += 256) {
    float nc = 0.99f * ec[i] + 0.01f * nacc[i];
    nc_s[i] = nc; part += nc;
  }
  red[tid] = part; __syncthreads();
  for (int s = 128; s > 0; s >>= 1) { if (tid < s) red[tid] += red[tid + s]; __syncthreads(); }
  float total = red[0];
  float scale = total / (total + (float)K_CB * 1e-5f);
  for (int i = tid; i < K_CB; i += 256) out_count[i] = (nc_s[i] + 1e-5f) * scale;
  __syncthreads();

  float ln = 0.f, lm = 0.f;
  for (int i = tid; i < 4096; i += 256) { ln += loss_part[i]; lm += mask_part[i]; }
  red[tid] = ln; __syncthreads();
  for (int s = 128; s > 0; s >>= 1) { if (tid < s) red[tid] += red[tid + s]; __syncthreads(); }
  ln = red[0]; __syncthreads();
  red[tid] = lm; __syncthreads();
  for (int s = 128; s > 0; s >>= 1) { if (tid < s) red[tid] += red[tid + s]; __syncthreads(); }
  lm = red[0];
  if (tid == 0) out_loss[0] = 2.5f * ln / lm;   // 10 * 0.25 * num/den
}

extern "C" void kernel_launch(void* const* d_in, const int* in_sizes, int n_in,
                              void* d_out, int out_size, void* d_ws, size_t ws_size,
                              hipStream_t stream) {
  const float* z          = (const float*)d_in[0];
  const float* mask       = (const float*)d_in[1];
  const float* codebook   = (const float*)d_in[2];
  const float* ema_count  = (const float*)d_in[3];
  const float* ema_weight = (const float*)d_in[4];

  float* out        = (float*)d_out;
  float* out0       = out;                         // 4194304
  float* out_idx    = out + 4194304;               // 16384
  float* out_loss   = out + 4210688;               // 1
  float* out_count  = out + 4210689;               // 4096
  float* out_weight = out + 4214785;               // 1048576

  char* ws = (char*)d_ws;
  unsigned short* zpack = (unsigned short*)(ws + WS_ZPACK);
  unsigned short* cpack = (unsigned short*)(ws + WS_CPACK);
  double* cnorm    = (double*)(ws + WS_CNORM);
  double* cand_val = (double*)(ws + WS_CANDV);
  int*    cand_idx = (int*)   (ws + WS_CANDI);
  float*  dw       = (float*) (ws + WS_DW);
  float*  nacc     = (float*) (ws + WS_NACC);
  float*  lpart    = (float*) (ws + WS_LPART);
  float*  mpart    = (float*) (ws + WS_MPART);

  (void)hipFuncSetAttribute((const void*)vq_gemm,
                            hipFuncAttributeMaxDynamicSharedMemorySize, 98304);
  (void)hipMemsetAsync(ws + WS_DW, 0, WS_ZERO_BYTES, stream);

  vq_split_z<<<4096, 256, 0, stream>>>(z, zpack);
  vq_split_c<<<1024, 256, 0, stream>>>(codebook, cpack, cnorm);
  vq_gemm<<<2048, 512, 98304, stream>>>(zpack, cpack, cnorm, cand_val, cand_idx);
  vq_merge_scatter<<<4096, 256, 0, stream>>>(cand_val, cand_idx, z, mask, codebook,
                                             out0, out_idx, dw, nacc, lpart, mpart);
  vq_finish_weight<<<1024, 256, 0, stream>>>(ema_weight, dw, out_weight);
  vq_finish_count<<<1, 256, 0, stream>>>(ema_count, nacc, lpart, mpart,
                                         out_count, out_loss);
}